// Round 4
// baseline (2240.082 us; speedup 1.0000x reference)
//
#include <hip/hip_runtime.h>
#include <hip/hip_cooperative_groups.h>

namespace cg = cooperative_groups;

#define NN   2048
#define FF   512
#define CC   128
#define WROW 2560            // FF + NN
#define INFV 1.0e9f

#define AL(p)   __hip_atomic_load((p), __ATOMIC_RELAXED, __HIP_MEMORY_SCOPE_AGENT)
#define AS(p,v) __hip_atomic_store((p), (v), __ATOMIC_RELAXED, __HIP_MEMORY_SCOPE_AGENT)

__device__ __forceinline__ unsigned enc(float x) { return __float_as_uint(x); }
__device__ __forceinline__ float dec(unsigned x) { return __uint_as_float(x); }

// Phase 1 (cooperative, 512x256 — the round-1 skeleton, which measured
// 1.13us/sweep including 2 grid.syncs): dense min-plus relax with per-block
// L1-resident 32KB adj slices + atomicMin publish. Fixed vs round 1:
//  - convergence flag READ is an AGENT atomic load (round 1's plain load was
//    stale/poisoned -> the break never fired and it ran all 2048 sweeps)
//  - AL is issued by thread 0 BEFORE the relax so L3 latency hides under it
//  - suffix-sum exchange (parts/Sarr) uses AGENT store/load + LDS broadcast
//  - epilogue GEMM moved to a second kernel; dist-fold partials staged in out
__global__ __launch_bounds__(256, 2)
void bf_phase1(const float* __restrict__ adj,
               const float* __restrict__ W,
               const int*   __restrict__ srcp,
               float*       __restrict__ out,
               unsigned*    __restrict__ ws_u,
               int out_size)
{
    cg::grid_group grid = cg::this_grid();
    const int t   = blockIdx.x * blockDim.x + threadIdx.x;   // 0..131071
    const int tid = threadIdx.x;
    const int src = *srcp;

    unsigned* buf0  = ws_u;
    unsigned* buf1  = ws_u + NN;
    unsigned* buf2  = ws_u + 2 * NN;
    unsigned* flags = ws_u + 3 * NN;                 // [0..NN]
    unsigned* partsu= ws_u + 3 * NN + 2064;          // NN words (suffix partials)
    unsigned* Sarru = partsu + NN;                   // CC words

    unsigned* bufs[3] = { buf0, buf1, buf2 };

    __shared__ unsigned s_flag;
    __shared__ float    SarrL[CC];

    // ---- init (replay-safe: everything rewritten every launch) ----
    if (t < NN) {
        buf0[t] = enc(t == src ? 0.0f : INFV);
        buf1[t] = 0xFFFFFFFFu;
        buf2[t] = 0xFFFFFFFFu;
    }
    if (t <= NN) flags[t] = 0u;

    // accumulator mapping: out elems e0=2t, e0+1 -> v = e0>>7, c = e0&127
    const int e0 = 2 * t;
    const int v  = e0 >> 7;
    const int c0 = e0 & 127;
    const float initd = (v == src) ? 0.0f : INFV;
    float acc0 = initd * W[(size_t)c0 * WROW + FF];          // column 0 = init
    float acc1 = initd * W[(size_t)(c0 + 1) * WROW + FF];

    grid.sync();

    // relax mapping: v-col = t & 2047, u-chunk = t >> 11 (64 chunks x 32 u)
    const int chunk = t >> 11;
    const int vA    = t & (NN - 1);
    const int u0    = chunk * 32;

    int kconv = -1;
    const unsigned* finalBuf = nullptr;
    int has_neg = 0;

    for (int s = 1; s <= NN; ++s) {
        const unsigned* cur   = bufs[(s - 1) % 3];
        unsigned*       nb    = bufs[s % 3];
        unsigned*       spare = bufs[(s + 1) % 3];

        // issue the convergence-flag load early; latency hides under relax
        unsigned fval = 1u;
        if (tid == 0 && s >= 2) fval = AL(&flags[s - 1]);

        // ---- relax: nb[v] = min(cur[v], min_u cur[u] + adj[u][v]) ----
        {
            float m = (chunk == 0) ? dec(cur[vA]) : 4.0e9f;
            const float* arow = adj + (size_t)u0 * NN + vA;
            #pragma unroll 8
            for (int i = 0; i < 32; ++i)
                m = fminf(m, dec(cur[u0 + i]) + arow[(size_t)i * NN]);
            atomicMin(&nb[vA], enc(m));   // nonneg floats: uint order == value
        }

        // ---- converged? (flag from sweep s-1, finalized before sweep s) ----
        if (s >= 2) {
            if (tid == 0) s_flag = fval;
            __syncthreads();
            if (s_flag == 0u) { kconv = s - 1; finalBuf = cur; break; }
        }
        grid.sync();

        // ---- phase B: change flag, fold column s, reset spare ----
        if (t < NN) {
            unsigned nv = nb[t];
            bool changed = (nv != cur[t]);
            unsigned long long bal = __ballot(changed);
            if ((tid & 63) == 0 && bal) atomicOr(&flags[s], 1u);
            if (s < NN) spare[t] = 0xFFFFFFFFu;
        }
        if (s < NN) {
            float dv = dec(nb[v]);
            acc0 = fmaf(dv, W[(size_t)c0 * WROW + FF + s], acc0);
            acc1 = fmaf(dv, W[(size_t)(c0 + 1) * WROW + FF + s], acc1);
        }
        grid.sync();
    }

    if (kconv < 0) {
        // ran all NN sweeps; sweep NN was the negative-cycle probe
        if (tid == 0) s_flag = AL(&flags[NN]);
        __syncthreads();
        has_neg = (s_flag != 0u) ? 1 : 0;
    } else if (kconv < NN - 1) {
        // columns kconv+1 .. NN-1 all equal final dist: suffix sums of W cols
        if (t < NN) {
            int c = t >> 4, part = t & 15;
            float ssum = 0.0f;
            for (int i = kconv + 1 + part; i <= NN - 1; i += 16)
                ssum += W[(size_t)c * WROW + FF + i];
            AS(&partsu[t], enc(ssum));
        }
        grid.sync();
        if (t < CC) {
            float x = 0.0f;
            #pragma unroll
            for (int p = 0; p < 16; ++p) x += dec(AL(&partsu[t * 16 + p]));
            AS(&Sarru[t], enc(x));
        }
        grid.sync();
        if (tid < CC) SarrL[tid] = dec(AL(&Sarru[tid]));   // per-block broadcast
        __syncthreads();
        float dv = dec(finalBuf[v]);
        acc0 = fmaf(dv, SarrL[c0], acc0);
        acc1 = fmaf(dv, SarrL[c0 + 1], acc1);
    }

    // ---- stage dist-fold partials in out; epilogue kernel finishes ----
    *(float2*)(out + e0) = make_float2(acc0, acc1);
    if (t == 0 && out_size > NN * CC) out[NN * CC] = has_neg ? 1.0f : 0.0f;
}

// Phase 2 (plain launch, 256 blocks x 256): out += emb @ Wemb^T + bias.
// Cross-kernel stream ordering guarantees visibility of phase-1 stores.
__global__ __launch_bounds__(256, 4)
void gnn_epilogue(const float* __restrict__ emb,
                  const float* __restrict__ W,
                  const float* __restrict__ bias,
                  float*       __restrict__ out)
{
    __shared__ __align__(16) float Elds[8 * FF];     // 16384 B
    __shared__ float Wt[CC * 34];                    // 17408 B
    const int tid = threadIdx.x, b = blockIdx.x;

    // stage 8 emb rows (coalesced float4)
    #pragma unroll
    for (int qq = 0; qq < 4; ++qq) {
        int r = tid + 256 * qq;                      // 0..1023
        int v = r >> 7, i4 = (r & 127) * 4;
        *(float4*)(Elds + v * FF + i4) =
            *(const float4*)(emb + (size_t)(8 * b + v) * FF + i4);
    }

    const int v2 = tid >> 5;                         // 0..7
    const int cgi = tid & 31;                        // c = cgi + 32j
    float acc[4];
    #pragma unroll
    for (int j = 0; j < 4; ++j)
        acc[j] = out[(size_t)(8 * b + v2) * CC + cgi + 32 * j];
    __syncthreads();

    for (int chk = 0; chk < FF / 32; ++chk) {
        #pragma unroll
        for (int qq = 0; qq < 4; ++qq) {
            int r = tid + 256 * qq;
            int c = r >> 3, i4 = (r & 7) * 4;
            float4 w4 = *(const float4*)(W + (size_t)c * WROW + 32 * chk + i4);
            Wt[c * 34 + i4 + 0] = w4.x;
            Wt[c * 34 + i4 + 1] = w4.y;
            Wt[c * 34 + i4 + 2] = w4.z;
            Wt[c * 34 + i4 + 3] = w4.w;
        }
        __syncthreads();
        #pragma unroll
        for (int i = 0; i < 32; i += 2) {
            float2 e2 = *(float2*)(Elds + v2 * FF + 32 * chk + i);
            #pragma unroll
            for (int j = 0; j < 4; ++j) {
                float2 w2 = *(float2*)(Wt + (cgi + 32 * j) * 34 + i);
                acc[j] = fmaf(e2.x, w2.x, acc[j]);
                acc[j] = fmaf(e2.y, w2.y, acc[j]);
            }
        }
        __syncthreads();
    }

    #pragma unroll
    for (int j = 0; j < 4; ++j) {
        int c = cgi + 32 * j;
        out[(size_t)(8 * b + v2) * CC + c] = acc[j] + bias[c];
    }
}

extern "C" void kernel_launch(void* const* d_in, const int* in_sizes, int n_in,
                              void* d_out, int out_size, void* d_ws, size_t ws_size,
                              hipStream_t stream) {
    const float* adj  = (const float*)d_in[0];
    const float* emb  = (const float*)d_in[1];
    const float* W    = (const float*)d_in[2];
    const float* bias = (const float*)d_in[3];
    const int*   srcp = (const int*)d_in[4];
    float* outp = (float*)d_out;
    unsigned* ws = (unsigned*)d_ws;
    int osz = out_size;

    void* args[] = { (void*)&adj, (void*)&W, (void*)&srcp,
                     (void*)&outp, (void*)&ws, (void*)&osz };
    hipLaunchCooperativeKernel((const void*)bf_phase1,
                               dim3(512), dim3(256), args, 0, stream);
    gnn_epilogue<<<dim3(256), dim3(256), 0, stream>>>(emb, W, bias, outp);
}

// Round 5
// 204.594 us; speedup vs baseline: 10.9489x; 10.9489x over previous
//
#include <hip/hip_runtime.h>
#include <hip/hip_cooperative_groups.h>

namespace cg = cooperative_groups;

#define NN   2048
#define FF   512
#define CC   128
#define WROW 2560            // FF + NN
#define INFV 1.0e9f
#define NB   256             // blocks (1/CU)
#define NT   1024            // threads/block
#define BN   8               // v-columns per block

#define AL(p)    __hip_atomic_load((p), __ATOMIC_RELAXED, __HIP_MEMORY_SCOPE_AGENT)
#define AS(p,v)  __hip_atomic_store((p), (v), __ATOMIC_RELAXED, __HIP_MEMORY_SCOPE_AGENT)
#define AADD(p,v) __hip_atomic_fetch_add((p), (v), __ATOMIC_RELAXED, __HIP_MEMORY_SCOPE_AGENT)

struct WS {
    unsigned D[2][NN];   // dist ping-pong (float bits), AGENT-only access
    unsigned bar[4];     // combined barrier+change slots, recycled mod 4
    unsigned Suf[CC];    // suffix sums (float bits)
};

__device__ __forceinline__ unsigned enc(float x){ return __float_as_uint(x); }
__device__ __forceinline__ float dec(unsigned x){ return __uint_as_float(x); }

// Phase 1: dense Bellman-Ford with LDS-resident adjacency slices.
// ALL cross-block state (D, bar, Suf) moves ONLY through AGENT-scope atomics
// (the round-2-proven protocol); all cross-block publishes are issued by
// wave 0 so the barrier's s_waitcnt vmcnt(0) (tid 0, same wave) drains them.
__global__ __launch_bounds__(NT, 1)
void bf_phase1(const float* __restrict__ adj,
               const float* __restrict__ W,
               const int*   __restrict__ srcp,
               float*       __restrict__ out,
               WS* ws, int out_size)
{
    __shared__ __align__(16) float adjT[BN * NN];  // 64 KB: adjT[vs][u]
    __shared__ float dist[NN];                     // 8 KB
    __shared__ float red[16];
    __shared__ float dcol[BN];
    __shared__ float dprev[BN];
    __shared__ float SufL[CC];
    __shared__ unsigned s_u;

    const int tid = threadIdx.x;
    const int b   = blockIdx.x;
    const int t   = b * NT + tid;
    const int src = *srcp;
    const int vb  = b * BN;

    // ---- init ws (AGENT stores only; rewritten every launch -> replay-safe) ----
    if (t < NN) AS(&ws->D[0][t], enc(t == src ? 0.0f : INFV));
    if (t < 4)  AS(&ws->bar[t], 0u);

    // ---- stage adjacency column-slice: adjT[vs][u] = adj[u][vb+vs] ----
    #pragma unroll
    for (int k = 0; k < NN / NT; ++k) {
        int u = tid + NT * k;
        const float* rp = adj + (size_t)u * NN + vb;
        float4 a  = *(const float4*)rp;
        float4 c4 = *(const float4*)(rp + 4);
        adjT[0*NN+u]=a.x;  adjT[1*NN+u]=a.y;  adjT[2*NN+u]=a.z;  adjT[3*NN+u]=a.w;
        adjT[4*NN+u]=c4.x; adjT[5*NN+u]=c4.y; adjT[6*NN+u]=c4.z; adjT[7*NN+u]=c4.w;
    }
    if (tid < BN) dprev[tid] = ((vb + tid) == src) ? 0.0f : INFV;

    // out elem per thread: v = vb + (tid>>7), c = tid & 127
    const int vown = tid >> 7;
    const int c    = tid & 127;
    float accv;
    { float d0 = ((vb + vown) == src) ? 0.0f : INFV;   // column 0 = init
      accv = d0 * W[(size_t)c * WROW + FF]; }

    cg::this_grid().sync();   // one heavy sync: publishes init everywhere

    const int li = tid & 127;          // 128 threads per v-slot (vown)
    int kconv = -1;

    for (int s = 1; s <= NN; ++s) {
        // ---- gather dist_{s-1} (coalesced AGENT loads from L3) ----
        {
            const unsigned* Dp = ws->D[(s - 1) & 1];
            #pragma unroll
            for (int k = 0; k < NN / NT; ++k) {
                int i = tid + NT * k;
                dist[i] = dec(AL((unsigned*)&Dp[i]));
            }
        }
        __syncthreads();

        // W fold-column load issued early; consumed after the reduce
        float wv = (s < NN) ? W[(size_t)c * WROW + FF + s] : 0.0f;

        // ---- relax own 8 columns, pure LDS (conflict-free stride-128) ----
        float m = 4.0e9f;
        const float* ar = adjT + vown * NN;
        #pragma unroll
        for (int k = 0; k < 16; ++k) {
            int u = li + 128 * k;
            m = fminf(m, dist[u] + ar[u]);
        }
        #pragma unroll
        for (int st = 1; st < 64; st <<= 1) m = fminf(m, __shfl_xor(m, st, 64));
        if ((tid & 63) == 0) red[tid >> 6] = m;
        __syncthreads();

        unsigned ch = 0;
        if (tid < BN) {                 // wave 0: combine + publish own dists
            float nv = fminf(dprev[tid], fminf(red[2 * tid], red[2 * tid + 1]));
            dcol[tid] = nv;
            AS(&ws->D[s & 1][vb + tid], enc(nv));
            ch = (nv != dprev[tid]) ? 1u : 0u;
            dprev[tid] = nv;
        }
        unsigned long long bal = __ballot(ch != 0);   // wave0 lanes 0..7
        __syncthreads();                              // dcol ready

        if (s < NN) accv = fmaf(dcol[vown], wv, accv);  // fold column s

        // ---- combined barrier + change aggregation (round-2 protocol) ----
        if (tid == 0) {
            unsigned payload = 1u | (((bal & 0xFFull) ? 1u : 0u) << 16);
            asm volatile("s_waitcnt vmcnt(0)" ::: "memory");  // drain D publishes
            AADD(&ws->bar[s & 3], payload);
            unsigned v;
            do { __builtin_amdgcn_s_sleep(2); v = AL(&ws->bar[s & 3]); }
            while ((v & 0xFFFFu) < NB);
            s_u = v >> 16;                            // any block changed?
            if (b == 0) AS(&ws->bar[(s + 2) & 3], 0u); // recycle dead slot
        }
        __syncthreads();
        if (s_u == 0u) { kconv = s; break; }          // dist_s == dist_{s-1}
    }

    int hneg = (kconv < 0) ? 1 : 0;   // ran all NN sweeps incl. probe, still changing

    // ---- tail: columns kconv+1 .. NN-1 all equal final dist ----
    if (kconv >= 1 && kconv <= NN - 2) {
        if (b < CC) {                  // block b computes Suf[c = b]
            float ssum = 0.0f;
            for (int i = kconv + 1 + tid; i <= NN - 1; i += NT)
                ssum += W[(size_t)b * WROW + FF + i];
            #pragma unroll
            for (int st = 1; st < 64; st <<= 1) ssum += __shfl_xor(ssum, st, 64);
            if ((tid & 63) == 0) red[tid >> 6] = ssum;
            __syncthreads();
            if (tid == 0) {
                float x = 0.0f;
                #pragma unroll
                for (int w2 = 0; w2 < 16; ++w2) x += red[w2];
                AS(&ws->Suf[b], enc(x));
            }
        }
        {   // barrier on a fresh slot ((kconv+1)&3 was reset at sweep kconv-1)
            const int s2 = kconv + 1;
            if (tid == 0) {
                asm volatile("s_waitcnt vmcnt(0)" ::: "memory");  // drain Suf
                AADD(&ws->bar[s2 & 3], 1u);
                unsigned v;
                do { __builtin_amdgcn_s_sleep(2); v = AL(&ws->bar[s2 & 3]); }
                while ((v & 0xFFFFu) < NB);
            }
            __syncthreads();
        }
        if (tid < CC) SufL[tid] = dec(AL(&ws->Suf[tid]));
        __syncthreads();
        accv = fmaf(dcol[vown], SufL[c], accv);
    }

    // ---- publish partials through out; epilogue kernel finishes ----
    out[(size_t)(vb + vown) * CC + c] = accv;
    if (b == 0 && tid == 0 && out_size > NN * CC)
        out[NN * CC] = hneg ? 1.0f : 0.0f;
}

// Phase 2 (plain launch, proven in round 4): out += emb @ Wemb^T + bias.
// Cross-kernel stream ordering guarantees visibility of phase-1 stores.
__global__ __launch_bounds__(256, 4)
void gnn_epilogue(const float* __restrict__ emb,
                  const float* __restrict__ W,
                  const float* __restrict__ bias,
                  float*       __restrict__ out)
{
    __shared__ __align__(16) float Elds[8 * FF];     // 16384 B
    __shared__ float Wt[CC * 34];                    // 17408 B
    const int tid = threadIdx.x, b = blockIdx.x;

    #pragma unroll
    for (int qq = 0; qq < 4; ++qq) {
        int r = tid + 256 * qq;                      // 0..1023
        int v = r >> 7, i4 = (r & 127) * 4;
        *(float4*)(Elds + v * FF + i4) =
            *(const float4*)(emb + (size_t)(8 * b + v) * FF + i4);
    }

    const int v2 = tid >> 5;                         // 0..7
    const int cgi = tid & 31;                        // c = cgi + 32j
    float acc[4];
    #pragma unroll
    for (int j = 0; j < 4; ++j)
        acc[j] = out[(size_t)(8 * b + v2) * CC + cgi + 32 * j];
    __syncthreads();

    for (int chk = 0; chk < FF / 32; ++chk) {
        #pragma unroll
        for (int qq = 0; qq < 4; ++qq) {
            int r = tid + 256 * qq;
            int c = r >> 3, i4 = (r & 7) * 4;
            float4 w4 = *(const float4*)(W + (size_t)c * WROW + 32 * chk + i4);
            Wt[c * 34 + i4 + 0] = w4.x;
            Wt[c * 34 + i4 + 1] = w4.y;
            Wt[c * 34 + i4 + 2] = w4.z;
            Wt[c * 34 + i4 + 3] = w4.w;
        }
        __syncthreads();
        #pragma unroll
        for (int i = 0; i < 32; i += 2) {
            float2 e2 = *(float2*)(Elds + v2 * FF + 32 * chk + i);
            #pragma unroll
            for (int j = 0; j < 4; ++j) {
                float2 w2 = *(float2*)(Wt + (cgi + 32 * j) * 34 + i);
                acc[j] = fmaf(e2.x, w2.x, acc[j]);
                acc[j] = fmaf(e2.y, w2.y, acc[j]);
            }
        }
        __syncthreads();
    }

    #pragma unroll
    for (int j = 0; j < 4; ++j) {
        int c = cgi + 32 * j;
        out[(size_t)(8 * b + v2) * CC + c] = acc[j] + bias[c];
    }
}

extern "C" void kernel_launch(void* const* d_in, const int* in_sizes, int n_in,
                              void* d_out, int out_size, void* d_ws, size_t ws_size,
                              hipStream_t stream) {
    const float* adj  = (const float*)d_in[0];
    const float* emb  = (const float*)d_in[1];
    const float* W    = (const float*)d_in[2];
    const float* bias = (const float*)d_in[3];
    const int*   srcp = (const int*)d_in[4];
    float* outp = (float*)d_out;
    WS* ws = (WS*)d_ws;
    int osz = out_size;

    void* args[] = { (void*)&adj, (void*)&W, (void*)&srcp,
                     (void*)&outp, (void*)&ws, (void*)&osz };
    hipLaunchCooperativeKernel((const void*)bf_phase1,
                               dim3(NB), dim3(NT), args, 0, stream);
    gnn_epilogue<<<dim3(256), dim3(256), 0, stream>>>(emb, W, bias, outp);
}

// Round 6
// 180.364 us; speedup vs baseline: 12.4198x; 1.1343x over previous
//
#include <hip/hip_runtime.h>
#include <hip/hip_cooperative_groups.h>

namespace cg = cooperative_groups;

#define NN   2048
#define FF   512
#define CC   128
#define WROW 2560            // FF + NN
#define INFV 1.0e9f
#define NB   128             // blocks (1/CU, 139KB LDS each)
#define NT   1024
#define BN   16              // v-columns per block (64B/row = HBM granule)
#define NG   8               // barrier groups
#define GRP  16              // blocks per group

#define AL(p)     __hip_atomic_load((p), __ATOMIC_RELAXED, __HIP_MEMORY_SCOPE_AGENT)
#define AS(p,v)   __hip_atomic_store((p), (v), __ATOMIC_RELAXED, __HIP_MEMORY_SCOPE_AGENT)
#define AADD(p,v) __hip_atomic_fetch_add((p), (v), __ATOMIC_RELAXED, __HIP_MEMORY_SCOPE_AGENT)

struct WS {
    unsigned D[2][NN];       // dist ping-pong (float bits), AGENT-only
    unsigned g1[4][NG][16];  // level-1 barrier counters, slot mod 4, line-padded
    unsigned glob[4][16];    // level-2 counters
    unsigned rel[4][16];     // release words
    unsigned Suf[CC];        // suffix sums (float bits)
};

__device__ __forceinline__ unsigned enc(float x){ return __float_as_uint(x); }
__device__ __forceinline__ float dec(unsigned x){ return __uint_as_float(x); }

// Fully fused: Bellman-Ford sweeps (LDS-resident adj slice, two-level AGENT
// barrier) + per-sweep W-column folds + emb@W^T GEMM chunked into the barrier
// spin slack + suffix tail + bias. Single cooperative kernel.
// ALL cross-block state moves ONLY through AGENT-scope atomics (r2/r5-proven).
__global__ __launch_bounds__(NT, 1)
void bf_fused(const float* __restrict__ adj,
              const float* __restrict__ emb,
              const float* __restrict__ W,
              const float* __restrict__ bias,
              const int*   __restrict__ srcp,
              float*       __restrict__ out,
              WS* ws, int out_size)
{
    __shared__ __align__(16) float adjT[BN * NN];   // 128 KB: adjT[vs][u]
    __shared__ __align__(16) float dist[NN];        // 8 KB
    __shared__ float wcol[CC];                      // fold W column
    __shared__ float red[BN];
    __shared__ float dcol[BN];
    __shared__ float dprev[BN];
    __shared__ unsigned s_rel;

    const int tid = threadIdx.x;
    const int b   = blockIdx.x;
    const int t   = b * NT + tid;
    const int src = *srcp;
    const int grp = b >> 4;

    // XCD-contiguous columns: XCD (b&7) owns a contiguous 256-column band
    const int q  = (b & 7) * GRP + (b >> 3);
    const int vb = q * BN;

    // ---- init ws (AGENT stores only; rewritten every launch -> replay-safe) --
    if (t < NN) AS(&ws->D[0][t], enc(t == src ? 0.0f : INFV));
    if (t < 4 * NG) AS(&ws->g1[t >> 3][t & 7][0], 0u);
    if (t < 4) { AS(&ws->glob[t][0], 0u); AS(&ws->rel[t][0], 0u); }

    // ---- stage adjacency slice: adjT[vs][u] = adj[u][vb+vs] (64B/row reads) --
    #pragma unroll
    for (int it = 0; it < (NN * 4) / NT; ++it) {
        int r = tid + NT * it;
        int u = r >> 2, qc = (r & 3) * 4;
        float4 a = *(const float4*)(adj + (size_t)u * NN + vb + qc);
        adjT[(qc + 0) * NN + u] = a.x;
        adjT[(qc + 1) * NN + u] = a.y;
        adjT[(qc + 2) * NN + u] = a.z;
        adjT[(qc + 3) * NN + u] = a.w;
    }
    if (tid < BN) dprev[tid] = ((vb + tid) == src) ? 0.0f : INFV;

    // fold mapping: wave = owned v slot; lane covers c0,c0+1
    const int vown = tid >> 6;
    const int lane = tid & 63;
    const int c0 = 2 * lane, c1 = c0 + 1;

    // emb mapping (different decomposition; combined via LDS at the end)
    const int vE = vb + (tid & 15);
    const int cE = 2 * (tid >> 4) & 127;          // 2*(tid>>4) mod 128
    const int cEh = 2 * (tid >> 4) >> 7;          // unused guard (always 0..)
    (void)cEh;
    float ea0 = 0.0f, ea1 = 0.0f;

    float acc0, acc1;
    { float d0 = ((vb + vown) == src) ? 0.0f : INFV;   // distances column 0
      acc0 = d0 * W[(size_t)c0 * WROW + FF];
      acc1 = d0 * W[(size_t)c1 * WROW + FF]; }

    cg::this_grid().sync();   // one heavy sync: publishes init everywhere

    int kconv = -1;
    for (int s = 1; s <= NN; ++s) {
        // ---- gather dist_{s-1} (coalesced AGENT loads) ----
        { const unsigned* Dp = ws->D[(s - 1) & 1];
          dist[tid]      = dec(AL((unsigned*)&Dp[tid]));
          dist[tid + NT] = dec(AL((unsigned*)&Dp[tid + NT])); }
        // wave1 stages the fold-W column (kills 16x redundant scattered loads)
        if (s < NN && vown == 1) {
            wcol[lane]      = W[(size_t)lane * WROW + FF + s];
            wcol[64 + lane] = W[(size_t)(64 + lane) * WROW + FF + s];
        }
        __syncthreads();

        // ---- relax own column (vs = vown), b128 LDS reads, conflict-free ----
        float m = 4.0e9f;
        const float* ar = adjT + vown * NN;
        #pragma unroll
        for (int k = 0; k < 8; ++k) {
            int u = 4 * lane + 256 * k;
            float4 dd = *(const float4*)(dist + u);
            float4 aa = *(const float4*)(ar + u);
            m = fminf(m, fminf(fminf(dd.x + aa.x, dd.y + aa.y),
                               fminf(dd.z + aa.z, dd.w + aa.w)));
        }
        #pragma unroll
        for (int st = 1; st < 64; st <<= 1) m = fminf(m, __shfl_xor(m, st, 64));
        if (lane == 0) red[vown] = m;
        __syncthreads();

        unsigned ch = 0;
        if (tid < BN) {                    // wave 0: combine + publish
            float nv = fminf(dprev[tid], red[tid]);
            dcol[tid] = nv;
            AS(&ws->D[s & 1][vb + tid], enc(nv));
            ch = (nv != dprev[tid]) ? 1u : 0u;
            dprev[tid] = nv;
        }
        unsigned long long bal = __ballot(ch != 0);   // wave0 lanes 0..15
        if (tid == 0) {                    // arrive (two-level, before fold/emb)
            unsigned chg = (bal & 0xFFFFull) ? 1u : 0u;
            asm volatile("s_waitcnt vmcnt(0)" ::: "memory");  // drain D publishes
            unsigned pay = 1u | (chg << 16);
            unsigned tot = AADD(&ws->g1[s & 3][grp][0], pay) + pay;
            if ((tot & 0xFFFFu) == GRP) {              // last in group
                unsigned p2 = 1u | (((tot >> 16) ? 1u : 0u) << 16);
                unsigned t2 = AADD(&ws->glob[s & 3][0], p2) + p2;
                if ((t2 & 0xFFFFu) == NG)              // last group
                    AS(&ws->rel[s & 3][0], 0x80000000u | ((t2 >> 16) ? 1u : 0u));
            }
        }
        __syncthreads();                   // dcol + wcol ready

        // ---- fold column s + one emb-GEMM chunk (hidden under barrier) ----
        if (s < NN) {
            float dv = dcol[vown];
            acc0 = fmaf(dv, wcol[c0], acc0);
            acc1 = fmaf(dv, wcol[c1], acc1);
        }
        if (s - 1 < FF / 32) {
            int i0 = 32 * (s - 1);
            const float4* ep = (const float4*)(emb + (size_t)vE * FF + i0);
            const float4* wa = (const float4*)(W + (size_t)cE * WROW + i0);
            const float4* wb = (const float4*)(W + (size_t)(cE + 1) * WROW + i0);
            #pragma unroll
            for (int j = 0; j < 8; ++j) {
                float4 e = ep[j], x = wa[j], y = wb[j];
                ea0 += e.x*x.x + e.y*x.y + e.z*x.z + e.w*x.w;
                ea1 += e.x*y.x + e.y*y.y + e.z*y.z + e.w*y.w;
            }
        }

        // ---- spin on release ----
        if (tid == 0) {
            unsigned r;
            do { __builtin_amdgcn_s_sleep(1); r = AL(&ws->rel[s & 3][0]); }
            while (!(r >> 31));
            s_rel = r & 1u;
            if (b == 0) {                   // recycle slot s+2 (distance-2, safe)
                int ns = (s + 2) & 3;
                #pragma unroll
                for (int g = 0; g < NG; ++g) AS(&ws->g1[ns][g][0], 0u);
                AS(&ws->glob[ns][0], 0u);
                AS(&ws->rel[ns][0], 0u);
            }
        }
        __syncthreads();
        if (s_rel == 0u) { kconv = s; break; }   // dist_s == dist_{s-1}
    }

    int hneg = (kconv < 0) ? 1 : 0;   // never converged through the probe sweep

    // ---- tail: columns kconv+1 .. NN-1 all equal final dist ----
    if (kconv >= 1 && kconv <= NN - 2) {
        float ssum = 0.0f;                       // block b computes Suf[c=b]
        for (int i = kconv + 1 + tid; i <= NN - 1; i += NT)
            ssum += W[(size_t)b * WROW + FF + i];
        #pragma unroll
        for (int st = 1; st < 64; st <<= 1) ssum += __shfl_xor(ssum, st, 64);
        if (lane == 0) red[vown] = ssum;
        __syncthreads();
        if (tid == 0) {
            float x = 0.0f;
            #pragma unroll
            for (int w = 0; w < BN; ++w) x += red[w];
            AS(&ws->Suf[b], enc(x));
            const int st2 = (kconv + 1) & 3;     // fresh slot (reset at kconv-1)
            asm volatile("s_waitcnt vmcnt(0)" ::: "memory");
            unsigned tot = AADD(&ws->g1[st2][grp][0], 1u) + 1u;
            if ((tot & 0xFFFFu) == GRP) {
                unsigned t2 = AADD(&ws->glob[st2][0], 1u) + 1u;
                if ((t2 & 0xFFFFu) == NG) AS(&ws->rel[st2][0], 0x80000000u);
            }
            unsigned r;
            do { __builtin_amdgcn_s_sleep(1); r = AL(&ws->rel[st2][0]); }
            while (!(r >> 31));
        }
        __syncthreads();
        float dv = dcol[vown];
        acc0 = fmaf(dv, dec(AL(&ws->Suf[c0])), acc0);
        acc1 = fmaf(dv, dec(AL(&ws->Suf[c1])), acc1);
    }

    // ---- leftover emb chunks (if converged before 16 sweeps) ----
    for (int chk = (kconv < 0 ? 16 : (kconv < 16 ? kconv : 16)); chk < 16; ++chk) {
        int i0 = 32 * chk;
        const float4* ep = (const float4*)(emb + (size_t)vE * FF + i0);
        const float4* wa = (const float4*)(W + (size_t)cE * WROW + i0);
        const float4* wb = (const float4*)(W + (size_t)(cE + 1) * WROW + i0);
        #pragma unroll
        for (int j = 0; j < 8; ++j) {
            float4 e = ep[j], x = wa[j], y = wb[j];
            ea0 += e.x*x.x + e.y*x.y + e.z*x.z + e.w*x.w;
            ea1 += e.x*y.x + e.y*y.y + e.z*y.z + e.w*y.w;
        }
    }

    // ---- combine emb-mapping results with fold-mapping, add bias, store ----
    float* comb = adjT;                          // reuse: [16][129] padded
    comb[(tid & 15) * 129 + cE]     = ea0;
    comb[(tid & 15) * 129 + cE + 1] = ea1;
    __syncthreads();
    float o0 = acc0 + comb[vown * 129 + c0] + bias[c0];
    float o1 = acc1 + comb[vown * 129 + c1] + bias[c1];
    *(float2*)(out + (size_t)(vb + vown) * CC + c0) = make_float2(o0, o1);
    if (b == 0 && tid == 0 && out_size > NN * CC)
        out[NN * CC] = hneg ? 1.0f : 0.0f;
}

extern "C" void kernel_launch(void* const* d_in, const int* in_sizes, int n_in,
                              void* d_out, int out_size, void* d_ws, size_t ws_size,
                              hipStream_t stream) {
    const float* adj  = (const float*)d_in[0];
    const float* emb  = (const float*)d_in[1];
    const float* W    = (const float*)d_in[2];
    const float* bias = (const float*)d_in[3];
    const int*   srcp = (const int*)d_in[4];
    float* outp = (float*)d_out;
    WS* ws = (WS*)d_ws;
    int osz = out_size;

    void* args[] = { (void*)&adj, (void*)&emb, (void*)&W, (void*)&bias,
                     (void*)&srcp, (void*)&outp, (void*)&ws, (void*)&osz };
    hipLaunchCooperativeKernel((const void*)bf_fused,
                               dim3(NB), dim3(NT), args, 0, stream);
}

// Round 7
// 161.600 us; speedup vs baseline: 13.8619x; 1.1161x over previous
//
#include <hip/hip_runtime.h>
#include <hip/hip_cooperative_groups.h>

namespace cg = cooperative_groups;

#define NN   2048
#define FF   512
#define CC   128
#define WROW 2560            // FF + NN
#define INFV 1.0e9f
#define NB   128             // blocks (1/CU)
#define NT   1024
#define BN   16              // v-columns per block

#define AL64(p)   __hip_atomic_load((p),  __ATOMIC_RELAXED, __HIP_MEMORY_SCOPE_AGENT)
#define AS64(p,v) __hip_atomic_store((p), (v), __ATOMIC_RELAXED, __HIP_MEMORY_SCOPE_AGENT)

// All cross-block exchange is self-describing (tag,value) 8B words written by
// single dwordx2 stores (atomic at the coherent point). NO barriers, NO
// counters, NO fences in the sweep loop: consumers spin on the tags of the
// exact words they need. Convergence is detected LOCALLY by every block
// (each gathers the full vector, so dist_s == dist_{s-1} is a local test
// with a grid-identical outcome). Ping-pong slots are sufficient: a block
// at sweep s+1 has seen all tags s, which implies every block finished
// gathering s-1, so the slot it overwrites has no pending readers.
struct WS {
    unsigned long long D[2][NN];   // (tag<<32)|float_bits, ping-pong by sweep parity
    unsigned long long Suf[CC];    // suffix sums, tag = 0x40000000 + kconv
};

__device__ __forceinline__ unsigned long long pk(unsigned tag, float v) {
    return ((unsigned long long)tag << 32) | (unsigned long long)__float_as_uint(v);
}
__device__ __forceinline__ unsigned tg(unsigned long long e) { return (unsigned)(e >> 32); }
__device__ __forceinline__ float    vl(unsigned long long e) { return __uint_as_float((unsigned)e); }

__global__ __launch_bounds__(NT, 1)
void bf_tagged(const float* __restrict__ adj,
               const float* __restrict__ emb,
               const float* __restrict__ W,
               const float* __restrict__ bias,
               const int*   __restrict__ srcp,
               float*       __restrict__ out,
               WS* ws, int out_size)
{
    __shared__ __align__(16) float adjT[BN * NN];   // 128 KB: adjT[vs][u]
    __shared__ __align__(16) float dist[NN];        // 8 KB (current gathered vector)
    __shared__ float wcol[2][CC];                   // fold W column, parity-buffered
    __shared__ float red[BN];                       // per-wave relax mins
    __shared__ float dprevP[2][BN];                 // own prev dists, parity-buffered
    __shared__ unsigned redc[BN];                   // per-wave change flags

    const int tid = threadIdx.x;
    const int b   = blockIdx.x;
    const int src = *srcp;
    // XCD-contiguous column bands
    const int q  = (b & 7) * 16 + (b >> 3);
    const int vb = q * BN;

    // ---- init ws (rewritten every launch BEFORE the one cg.sync -> replay-safe,
    //      and stale same-tag values from a previous replay are erased) ----
    if (tid < BN) {
        int v = vb + tid;
        AS64(&ws->D[0][v], pk(0u, (v == src) ? 0.0f : INFV));   // dist_0, tag 0
        AS64(&ws->D[1][v], pk(0xFFFFFFFFu, 0.0f));              // sentinel
        if (tid == 0) AS64(&ws->Suf[b], 0ull);
    }

    // ---- stage adjacency slice: adjT[vs][u] = adj[u][vb+vs] (64B/row reads) ----
    #pragma unroll
    for (int it = 0; it < (NN * 4) / NT; ++it) {
        int r = tid + NT * it;
        int u = r >> 2, qc = (r & 3) * 4;
        float4 a = *(const float4*)(adj + (size_t)u * NN + vb + qc);
        adjT[(qc + 0) * NN + u] = a.x;
        adjT[(qc + 1) * NN + u] = a.y;
        adjT[(qc + 2) * NN + u] = a.z;
        adjT[(qc + 3) * NN + u] = a.w;
    }
    dist[tid]      = (tid == src) ? 0.0f : INFV;
    dist[tid + NT] = ((tid + NT) == src) ? 0.0f : INFV;
    if (tid < BN) {
        float d = ((vb + tid) == src) ? 0.0f : INFV;
        dprevP[0][tid] = d; dprevP[1][tid] = d;
    }

    const int vown = tid >> 6;            // wave w relaxes column vb+w
    const int lane = tid & 63;
    const int c0 = 2 * lane, c1 = c0 + 1; // fold/output c pair
    const int vE = vb + (tid & 15);       // emb-GEMM mapping
    const int cE = (2 * (tid >> 4)) & 127;
    const int u2 = 2 * tid;               // this thread's gather pair
    float ea0 = 0.0f, ea1 = 0.0f;

    float acc0, acc1;
    { float d0 = ((vb + vown) == src) ? 0.0f : INFV;   // distances column 0
      acc0 = d0 * W[(size_t)c0 * WROW + FF];
      acc1 = d0 * W[(size_t)c1 * WROW + FF]; }

    cg::this_grid().sync();   // the ONLY grid barrier: publishes init + resets

    int kconv = -1, hneg = 0;

    for (int s = 1; s <= NN; ++s) {
        // ---- gather dist_{s-1} (tag s-1): per-thread spin on own 2 words ----
        unsigned long long* Dq = ws->D[(s - 1) & 1];
        const unsigned want = (unsigned)(s - 1);
        if (vown == 1 && s < NN) {        // wave 1 stages fold-W column s
            wcol[s & 1][lane]      = W[(size_t)lane * WROW + FF + s];
            wcol[s & 1][64 + lane] = W[(size_t)(64 + lane) * WROW + FF + s];
        }
        unsigned long long e0 = AL64(&Dq[u2]), e1 = AL64(&Dq[u2 + 1]);
        while (tg(e0) != want) { __builtin_amdgcn_s_sleep(1); e0 = AL64(&Dq[u2]); }
        while (tg(e1) != want) { __builtin_amdgcn_s_sleep(1); e1 = AL64(&Dq[u2 + 1]); }
        float n0 = vl(e0), n1 = vl(e1);
        unsigned ch = (n0 != dist[u2]) | (n1 != dist[u2 + 1]);   // vs dist_{s-2}
        dist[u2] = n0; dist[u2 + 1] = n1;
        unsigned long long bal = __ballot(ch != 0);
        if (lane == 0) redc[vown] = (bal != 0ull) ? 1u : 0u;
        __syncthreads();                                   // sync A

        unsigned any = 0;
        #pragma unroll
        for (int w = 0; w < BN; ++w) any |= redc[w];       // broadcast LDS reads
        if (s >= 2 && !any) { kconv = s - 1; break; }      // fixed point (local!)

        // ---- relax own column over full LDS dist ----
        float m = 4.0e9f;
        const float* ar = adjT + vown * NN;
        #pragma unroll
        for (int k = 0; k < 8; ++k) {
            int u = 4 * lane + 256 * k;
            float4 dd = *(const float4*)(dist + u);
            float4 aa = *(const float4*)(ar + u);
            m = fminf(m, fminf(fminf(dd.x + aa.x, dd.y + aa.y),
                               fminf(dd.z + aa.z, dd.w + aa.w)));
        }
        #pragma unroll
        for (int st = 1; st < 64; st <<= 1) m = fminf(m, __shfl_xor(m, st, 64));
        if (lane == 0) red[vown] = m;
        __syncthreads();                                   // sync B

        // every thread recomputes nv locally (no extra sync); wave0 publishes
        float nv = fminf(dprevP[(s - 1) & 1][vown], red[vown]);
        if (tid < BN) {
            float nv2 = fminf(dprevP[(s - 1) & 1][tid], red[tid]);
            AS64(&ws->D[s & 1][vb + tid], pk((unsigned)s, nv2));
            dprevP[s & 1][tid] = nv2;
        }
        if (s < NN) {                                       // fold column s
            acc0 = fmaf(nv, wcol[s & 1][c0], acc0);
            acc1 = fmaf(nv, wcol[s & 1][c1], acc1);
        }
        if (s - 1 < 16) {                                   // emb-GEMM chunk
            int i0 = 32 * (s - 1);
            const float4* ep = (const float4*)(emb + (size_t)vE * FF + i0);
            const float4* wa = (const float4*)(W + (size_t)cE * WROW + i0);
            const float4* wb = (const float4*)(W + (size_t)(cE + 1) * WROW + i0);
            #pragma unroll
            for (int j = 0; j < 8; ++j) {
                float4 e = ep[j], x = wa[j], y = wb[j];
                ea0 += e.x*x.x + e.y*x.y + e.z*x.z + e.w*x.w;
                ea1 += e.x*y.x + e.y*y.y + e.z*y.z + e.w*y.w;
            }
        }
    }

    if (kconv < 0) {
        // never converged: sweep NN was the probe; gather dist_NN, compare local
        unsigned long long* Dq = ws->D[NN & 1];
        unsigned long long e0 = AL64(&Dq[u2]), e1 = AL64(&Dq[u2 + 1]);
        while (tg(e0) != NN) { __builtin_amdgcn_s_sleep(1); e0 = AL64(&Dq[u2]); }
        while (tg(e1) != NN) { __builtin_amdgcn_s_sleep(1); e1 = AL64(&Dq[u2 + 1]); }
        unsigned ch = (vl(e0) != dist[u2]) | (vl(e1) != dist[u2 + 1]);
        unsigned long long bal = __ballot(ch != 0);
        if (lane == 0) redc[vown] = (bal != 0ull) ? 1u : 0u;
        __syncthreads();
        unsigned any = 0;
        #pragma unroll
        for (int w = 0; w < BN; ++w) any |= redc[w];
        hneg = any ? 1 : 0;
    } else if (kconv >= 1 && kconv <= NN - 2) {
        // tail: columns kconv+1 .. NN-1 all equal final dist (in LDS dist[])
        float ssum = 0.0f;                      // block b computes Suf[c = b]
        for (int i = kconv + 1 + tid; i <= NN - 1; i += NT)
            ssum += W[(size_t)b * WROW + FF + i];
        #pragma unroll
        for (int st = 1; st < 64; st <<= 1) ssum += __shfl_xor(ssum, st, 64);
        if (lane == 0) red[vown] = ssum;
        __syncthreads();
        if (tid == 0) {
            float x = 0.0f;
            #pragma unroll
            for (int w = 0; w < BN; ++w) x += red[w];
            AS64(&ws->Suf[b], pk(0x40000000u + (unsigned)kconv, x));
        }
        const unsigned wantS = 0x40000000u + (unsigned)kconv;   // grid-identical
        unsigned long long s0 = AL64(&ws->Suf[c0]), s1 = AL64(&ws->Suf[c1]);
        while (tg(s0) != wantS) { __builtin_amdgcn_s_sleep(1); s0 = AL64(&ws->Suf[c0]); }
        while (tg(s1) != wantS) { __builtin_amdgcn_s_sleep(1); s1 = AL64(&ws->Suf[c1]); }
        float dv = dist[vb + vown];
        acc0 = fmaf(dv, vl(s0), acc0);
        acc1 = fmaf(dv, vl(s1), acc1);
    }

    // ---- leftover emb chunks (only if converged before 16 sweeps) ----
    for (int chk = (kconv < 0 ? 16 : (kconv < 16 ? kconv : 16)); chk < 16; ++chk) {
        int i0 = 32 * chk;
        const float4* ep = (const float4*)(emb + (size_t)vE * FF + i0);
        const float4* wa = (const float4*)(W + (size_t)cE * WROW + i0);
        const float4* wb = (const float4*)(W + (size_t)(cE + 1) * WROW + i0);
        #pragma unroll
        for (int j = 0; j < 8; ++j) {
            float4 e = ep[j], x = wa[j], y = wb[j];
            ea0 += e.x*x.x + e.y*x.y + e.z*x.z + e.w*x.w;
            ea1 += e.x*y.x + e.y*y.y + e.z*y.z + e.w*y.w;
        }
    }

    // ---- combine the two decompositions in LDS, add bias, store ----
    __syncthreads();                       // all done with adjT -> reuse as comb
    float* comb = adjT;                    // [16][129] padded
    comb[(tid & 15) * 129 + cE]     = ea0;
    comb[(tid & 15) * 129 + cE + 1] = ea1;
    __syncthreads();
    float o0 = acc0 + comb[vown * 129 + c0] + bias[c0];
    float o1 = acc1 + comb[vown * 129 + c1] + bias[c1];
    *(float2*)(out + (size_t)(vb + vown) * CC + c0) = make_float2(o0, o1);
    if (b == 0 && tid == 0 && out_size > NN * CC)
        out[NN * CC] = hneg ? 1.0f : 0.0f;
}

extern "C" void kernel_launch(void* const* d_in, const int* in_sizes, int n_in,
                              void* d_out, int out_size, void* d_ws, size_t ws_size,
                              hipStream_t stream) {
    const float* adj  = (const float*)d_in[0];
    const float* emb  = (const float*)d_in[1];
    const float* W    = (const float*)d_in[2];
    const float* bias = (const float*)d_in[3];
    const int*   srcp = (const int*)d_in[4];
    float* outp = (float*)d_out;
    WS* ws = (WS*)d_ws;
    int osz = out_size;

    void* args[] = { (void*)&adj, (void*)&emb, (void*)&W, (void*)&bias,
                     (void*)&srcp, (void*)&outp, (void*)&ws, (void*)&osz };
    hipLaunchCooperativeKernel((const void*)bf_tagged,
                               dim3(NB), dim3(NT), args, 0, stream);
}

// Round 9
// 142.856 us; speedup vs baseline: 15.6807x; 1.1312x over previous
//
#include <hip/hip_runtime.h>

#define NN   2048
#define FF   512
#define CC   128
#define WROW 2560            // FF + NN
#define INFV 1.0e9f
#define NB   128             // blocks, 1/CU (140KB LDS), all co-resident
#define NT   1024
#define BN   16              // v-columns per block
#define MAGIC 0xB00F5EEDu    // init tag: cannot alias any sweep number

#define AL32(p)   __hip_atomic_load((p),  __ATOMIC_RELAXED, __HIP_MEMORY_SCOPE_AGENT)
#define AS32(p,v) __hip_atomic_store((p), (v), __ATOMIC_RELAXED, __HIP_MEMORY_SCOPE_AGENT)
#define AL64(p)   __hip_atomic_load((p),  __ATOMIC_RELAXED, __HIP_MEMORY_SCOPE_AGENT)
#define AS64(p,v) __hip_atomic_store((p), (v), __ATOMIC_RELAXED, __HIP_MEMORY_SCOPE_AGENT)

// Protocol (no grid sync, no cooperative launch, no barriers):
//  - data: D64[parity][NN/2] (8-aligned; each 32-bit half written AGENT by its
//    column owner), drained per-wave with s_waitcnt vmcnt(0) (r2/r5-proven
//    ack-then-signal); readers do ONE 64-bit atomic load per pair.
//  - signal: ONE line-padded tag per block per parity, = sweep number.
//    128 watcher threads/block poll 128 exclusive lines; data is then loaded
//    one-shot (no retry storm on shared data words — the r7 bottleneck).
//  - slot reuse (parity ping-pong) is safe by induction: block i publishes
//    sweep s only after seeing all tags s-1, which requires every block
//    finished its sweep-(s-1) watch/gather of parity s&1 — no pending readers.
//  - replay safety: the computation is deterministic, so any stale ws value
//    equals the value this launch will (re)write -> stale reads are correct.
//    First-call garbage is fenced by MAGIC tags (each block erases its T[1]
//    line BEFORE setting T[0]=MAGIC, and no block can pass the sweep-1 gate
//    until all T[0] are MAGIC — so garbage T[1] is unreachable).
struct WS {
    unsigned long long D64[2][NN / 2]; // dist float-bit pairs, parity ping-pong
    unsigned T[2][NB][16];             // per-block tags, one 64B line each
    unsigned long long Suf[CC][8];     // (tag<<32)|value suffix sums, line each
};

__device__ __forceinline__ unsigned long long pk(unsigned tag, float v) {
    return ((unsigned long long)tag << 32) | (unsigned long long)__float_as_uint(v);
}
__device__ __forceinline__ unsigned tg(unsigned long long e) { return (unsigned)(e >> 32); }
__device__ __forceinline__ float    vl(unsigned long long e) { return __uint_as_float((unsigned)e); }

__global__ __launch_bounds__(NT, 1)
void bf_nosync(const float* __restrict__ adj,
               const float* __restrict__ emb,
               const float* __restrict__ W,
               const float* __restrict__ bias,
               const int*   __restrict__ srcp,
               float*       __restrict__ out,
               WS* ws, int out_size)
{
    __shared__ __align__(16) float adjT[BN * NN];   // 128 KB: adjT[vs][u]
    __shared__ __align__(16) float dist[NN];        // 8 KB
    __shared__ float    wcol[CC];
    __shared__ float    red16[16];
    __shared__ unsigned redc[16];

    const int tid = threadIdx.x;
    const int b   = blockIdx.x;
    const int src = *srcp;
    const int q   = (b & 7) * 16 + (b >> 3);        // XCD-contiguous bands
    const int vb  = q * BN;

    // ---- ordered init publish (replaces grid.sync) ----
    if (tid == 0) AS32(&ws->T[1][b][0], MAGIC);
    if (tid < BN)
        AS32(((unsigned*)&ws->D64[0][0]) + (vb + tid),
             __float_as_uint(((vb + tid) == src) ? 0.0f : INFV));
    if (tid < 64) asm volatile("s_waitcnt vmcnt(0)" ::: "memory");
    if (tid == 0) AS32(&ws->T[0][b][0], MAGIC);

    // ---- stage adjacency slice: adjT[vs][u] = adj[u][vb+vs] (64B/row) ----
    #pragma unroll
    for (int it = 0; it < 8; ++it) {
        int r = tid + NT * it;
        int u = r >> 2, qc = (r & 3) * 4;
        float4 a = *(const float4*)(adj + (size_t)u * NN + vb + qc);
        adjT[(qc + 0) * NN + u] = a.x;
        adjT[(qc + 1) * NN + u] = a.y;
        adjT[(qc + 2) * NN + u] = a.z;
        adjT[(qc + 3) * NN + u] = a.w;
    }
    dist[tid]      = (tid == src) ? 0.0f : INFV;
    dist[tid + NT] = ((tid + NT) == src) ? 0.0f : INFV;
    __syncthreads();

    const int vown = tid >> 6;            // wave w owns column vb+w
    const int lane = tid & 63;
    const int c0 = 2 * lane, c1 = c0 + 1; // fold/output class pair
    const int vE = vb + (tid & 15);       // emb-GEMM mapping
    const int cE = (2 * (tid >> 4)) & 127;
    float ea0 = 0.0f, ea1 = 0.0f;
    float dprev_r = ((vb + vown) == src) ? 0.0f : INFV;   // own dist, in-reg

    float acc0, acc1;
    { float d0 = dprev_r;                                  // column 0 = init
      acc0 = d0 * W[(size_t)c0 * WROW + FF];
      acc1 = d0 * W[(size_t)c1 * WROW + FF]; }

    int kconv = -1, hneg = 0;

    for (int s = 1; s <= NN; ++s) {
        const int p = (s - 1) & 1;
        // ---- 1. watch: 128 threads poll 128 exclusive tag lines ----
        if (tid < NB) {
            const unsigned want = (s == 1) ? MAGIC : (unsigned)(s - 1);
            unsigned f = AL32(&ws->T[p][tid][0]);
            while (f != want) { __builtin_amdgcn_s_sleep(1); f = AL32(&ws->T[p][tid][0]); }
        }
        __syncthreads();
        // wave 1 stages this sweep's fold-W column
        if (s < NN && vown == 1) {
            wcol[lane]      = W[(size_t)lane * WROW + FF + s];
            wcol[64 + lane] = W[(size_t)(64 + lane) * WROW + FF + s];
        }
        // ---- 2. one-shot gather + local bitwise convergence test ----
        {
            unsigned long long e = AL64(&ws->D64[p][tid]);
            float n0 = __uint_as_float((unsigned)e);
            float n1 = __uint_as_float((unsigned)(e >> 32));
            unsigned ch = (n0 != dist[2 * tid]) | (n1 != dist[2 * tid + 1]);
            dist[2 * tid] = n0; dist[2 * tid + 1] = n1;
            unsigned long long bal = __ballot(ch != 0);
            if (lane == 0) redc[vown] = (bal != 0ull) ? 1u : 0u;
        }
        __syncthreads();
        unsigned any = 0;
        #pragma unroll
        for (int w = 0; w < 16; ++w) any |= redc[w];
        if (s >= 2 && !any) { kconv = s - 1; break; }   // grid-identical decision

        // ---- 3. emb-GEMM chunk (hidden under exchange latency) ----
        if (s - 1 < 16) {
            int i0 = 32 * (s - 1);
            const float4* ep = (const float4*)(emb + (size_t)vE * FF + i0);
            const float4* wa = (const float4*)(W + (size_t)cE * WROW + i0);
            const float4* wb = (const float4*)(W + (size_t)(cE + 1) * WROW + i0);
            #pragma unroll
            for (int j = 0; j < 8; ++j) {
                float4 e = ep[j], x = wa[j], y = wb[j];
                ea0 += e.x*x.x + e.y*x.y + e.z*x.z + e.w*x.w;
                ea1 += e.x*y.x + e.y*y.y + e.z*y.z + e.w*y.w;
            }
        }

        // ---- 4. relax own column, pure LDS ----
        float m = 4.0e9f;
        const float* ar = adjT + vown * NN;
        #pragma unroll
        for (int k = 0; k < 8; ++k) {
            int u = 4 * lane + 256 * k;
            float4 dd = *(const float4*)(dist + u);
            float4 aa = *(const float4*)(ar + u);
            m = fminf(m, fminf(fminf(dd.x + aa.x, dd.y + aa.y),
                               fminf(dd.z + aa.z, dd.w + aa.w)));
        }
        #pragma unroll
        for (int st = 1; st < 64; st <<= 1) m = fminf(m, __shfl_xor(m, st, 64));
        float nv = fminf(dprev_r, m);
        dprev_r = nv;

        // ---- 5. publish data; per-wave ack; then single tag ----
        if (lane == 0)
            AS32(((unsigned*)&ws->D64[s & 1][0]) + (vb + vown), __float_as_uint(nv));
        asm volatile("s_waitcnt vmcnt(0)" ::: "memory");   // ack own store
        __syncthreads();
        if (tid == 0) AS32(&ws->T[s & 1][b][0], (unsigned)s);

        // ---- 6. fold column s (overlaps other blocks' watch) ----
        if (s < NN) {
            acc0 = fmaf(nv, wcol[c0], acc0);
            acc1 = fmaf(nv, wcol[c1], acc1);
        }
    }

    if (kconv < 0) {
        // never converged: sweep NN was the probe; gather dist_NN, compare
        if (tid < NB) {
            unsigned f = AL32(&ws->T[0][tid][0]);          // NN&1 == 0
            while (f != (unsigned)NN) { __builtin_amdgcn_s_sleep(1); f = AL32(&ws->T[0][tid][0]); }
        }
        __syncthreads();
        unsigned long long e = AL64(&ws->D64[0][tid]);
        unsigned ch = (__uint_as_float((unsigned)e) != dist[2 * tid]) |
                      (__uint_as_float((unsigned)(e >> 32)) != dist[2 * tid + 1]);
        unsigned long long bal = __ballot(ch != 0);
        if (lane == 0) redc[vown] = (bal != 0ull) ? 1u : 0u;
        __syncthreads();
        unsigned any = 0;
        #pragma unroll
        for (int w = 0; w < 16; ++w) any |= redc[w];
        hneg = any ? 1 : 0;
    } else if (kconv >= 1 && kconv <= NN - 2) {
        // tail: columns kconv+1 .. NN-1 all equal final dist (in LDS)
        float ssum = 0.0f;                       // block b computes Suf[c = b]
        for (int i = kconv + 1 + tid; i <= NN - 1; i += NT)
            ssum += W[(size_t)b * WROW + FF + i];
        #pragma unroll
        for (int st = 1; st < 64; st <<= 1) ssum += __shfl_xor(ssum, st, 64);
        if (lane == 0) red16[vown] = ssum;
        __syncthreads();
        if (tid == 0) {
            float x = 0.0f;
            #pragma unroll
            for (int w = 0; w < 16; ++w) x += red16[w];
            AS64(&ws->Suf[b][0], pk(0x40000000u + (unsigned)kconv, x));
        }
        const unsigned wantS = 0x40000000u + (unsigned)kconv;   // grid-identical
        unsigned long long s0 = AL64(&ws->Suf[c0][0]);
        while (tg(s0) != wantS) { __builtin_amdgcn_s_sleep(1); s0 = AL64(&ws->Suf[c0][0]); }
        unsigned long long s1 = AL64(&ws->Suf[c1][0]);
        while (tg(s1) != wantS) { __builtin_amdgcn_s_sleep(1); s1 = AL64(&ws->Suf[c1][0]); }
        float dv = dist[vb + vown];
        acc0 = fmaf(dv, vl(s0), acc0);
        acc1 = fmaf(dv, vl(s1), acc1);
    }

    // ---- leftover emb chunks (only if converged before 16 sweeps) ----
    for (int chk = (kconv < 0 ? 16 : (kconv < 16 ? kconv : 16)); chk < 16; ++chk) {
        int i0 = 32 * chk;
        const float4* ep = (const float4*)(emb + (size_t)vE * FF + i0);
        const float4* wa = (const float4*)(W + (size_t)cE * WROW + i0);
        const float4* wb = (const float4*)(W + (size_t)(cE + 1) * WROW + i0);
        #pragma unroll
        for (int j = 0; j < 8; ++j) {
            float4 e = ep[j], x = wa[j], y = wb[j];
            ea0 += e.x*x.x + e.y*x.y + e.z*x.z + e.w*x.w;
            ea1 += e.x*y.x + e.y*y.y + e.z*y.z + e.w*y.w;
        }
    }

    // ---- combine decompositions in LDS, add bias, store ----
    __syncthreads();                       // adjT no longer needed -> reuse
    float* comb = adjT;                    // [16][129] padded
    comb[(tid & 15) * 129 + cE]     = ea0;
    comb[(tid & 15) * 129 + cE + 1] = ea1;
    __syncthreads();
    float o0 = acc0 + comb[vown * 129 + c0] + bias[c0];
    float o1 = acc1 + comb[vown * 129 + c1] + bias[c1];
    *(float2*)(out + (size_t)(vb + vown) * CC + c0) = make_float2(o0, o1);
    if (b == 0 && tid == 0 && out_size > NN * CC)
        out[NN * CC] = hneg ? 1.0f : 0.0f;
}

extern "C" void kernel_launch(void* const* d_in, const int* in_sizes, int n_in,
                              void* d_out, int out_size, void* d_ws, size_t ws_size,
                              hipStream_t stream) {
    const float* adj  = (const float*)d_in[0];
    const float* emb  = (const float*)d_in[1];
    const float* W    = (const float*)d_in[2];
    const float* bias = (const float*)d_in[3];
    const int*   srcp = (const int*)d_in[4];
    float* outp = (float*)d_out;
    WS* ws = (WS*)d_ws;
    int osz = out_size;

    bf_nosync<<<dim3(NB), dim3(NT), 0, stream>>>(adj, emb, W, bias, srcp,
                                                 outp, ws, osz);
}